// Round 14
// baseline (163.521 us; speedup 1.0000x reference)
//
#include <hip/hip_runtime.h>
#include <hip/hip_bf16.h>
#include <math.h>

#define NN 8192
#define DD 256
#define RR 32
#define KH 4
#define PP 128      // KH*RR
#define CAP 128     // max neighbors per row (mean ~34)
#define CAPL 128    // per-row capacity of lower/upper half-lists
#define NSTASH 48   // neighbors stashed in LDS (global fallback above)
#define ETA 0.5f
#define SCALE 0.17677669529663687f  // 1/sqrt(32)

// bf16 helpers (explicit bit ops: deterministic)
__device__ __forceinline__ unsigned short f2bf(float f) {
  union { float f; unsigned u; } v; v.f = f;
  unsigned r = v.u + 0x7fffu + ((v.u >> 16) & 1u);   // round-to-nearest-even
  return (unsigned short)(r >> 16);
}
__device__ __forceinline__ float bflo(unsigned u) { return __uint_as_float(u << 16); }
__device__ __forceinline__ float bfhi(unsigned u) { return __uint_as_float(u & 0xffff0000u); }

// ======== K1: Z-GEMM (0..255) | orth (256..265) | B2 (266..393) | Hb (394..649)
//              | paired symmetric lower-triangle A-scan (650..4745) =======================
// Scan: block p handles rows {NN-1-p, p} (constant work); thread tid owns cols
// [32*tid, 32*tid+32) -> one 128B line/thread, ONE block prefix per row (2 barriers).
__global__ __launch_bounds__(256) void zgemm_scan(const float* __restrict__ A,
                                                  const float* __restrict__ H,
                                                  const float* __restrict__ U,
                                                  float* __restrict__ B2,
                                                  unsigned short* __restrict__ Zb,
                                                  unsigned short* __restrict__ Hb,
                                                  float* __restrict__ orth_part,
                                                  int* __restrict__ lowCols,
                                                  int* __restrict__ lowCnt,
                                                  int* __restrict__ upCols,
                                                  int* __restrict__ upCnt) {
  __shared__ float smem[5152];
  int tid = threadIdx.x;
  int bx = blockIdx.x;
  int lane = tid & 63, wv = tid >> 6;

  if (bx >= 650) {
    int p = bx - 650;          // 0..4095
    __shared__ int wsum2[4];
#pragma unroll
    for (int half = 0; half < 2; ++half) {
      int row = (half == 0) ? (NN - 1 - p) : p;
      int limit = row;                     // strict lower: col < row
      int base0 = tid * 32;
      const float* a = A + (size_t)row * NN + base0;
      float4 v[8];
      int cnt = 0;
#pragma unroll
      for (int c = 0; c < 8; ++c) {
        if (base0 + c * 4 < limit) {
          v[c] = *(const float4*)(a + c * 4);
          cnt += (base0 + c * 4 + 0 < limit && v[c].x != 0.f);
          cnt += (base0 + c * 4 + 1 < limit && v[c].y != 0.f);
          cnt += (base0 + c * 4 + 2 < limit && v[c].z != 0.f);
          cnt += (base0 + c * 4 + 3 < limit && v[c].w != 0.f);
        }
      }
      int incl = cnt;
#pragma unroll
      for (int off = 1; off < 64; off <<= 1) {
        int t = __shfl_up(incl, off);
        if (lane >= off) incl += t;
      }
      if (lane == 63) wsum2[wv] = incl;
      __syncthreads();
      int base = 0;
#pragma unroll
      for (int w = 0; w < 4; ++w) if (w < wv) base += wsum2[w];
      int o = base + incl - cnt;           // exclusive prefix (ascending col order)
      int total = wsum2[0] + wsum2[1] + wsum2[2] + wsum2[3];
#pragma unroll
      for (int c = 0; c < 8; ++c) {
        if (base0 + c * 4 < limit) {
          float4 x = v[c];
          int col = base0 + c * 4;
          if (col + 0 < limit && x.x != 0.f) { if (o < CAPL) { lowCols[(size_t)row * CAPL + o] = col + 0; int s = atomicAdd(&upCnt[col + 0], 1); if (s < CAPL) upCols[(size_t)(col + 0) * CAPL + s] = row; } o++; }
          if (col + 1 < limit && x.y != 0.f) { if (o < CAPL) { lowCols[(size_t)row * CAPL + o] = col + 1; int s = atomicAdd(&upCnt[col + 1], 1); if (s < CAPL) upCols[(size_t)(col + 1) * CAPL + s] = row; } o++; }
          if (col + 2 < limit && x.z != 0.f) { if (o < CAPL) { lowCols[(size_t)row * CAPL + o] = col + 2; int s = atomicAdd(&upCnt[col + 2], 1); if (s < CAPL) upCols[(size_t)(col + 2) * CAPL + s] = row; } o++; }
          if (col + 3 < limit && x.w != 0.f) { if (o < CAPL) { lowCols[(size_t)row * CAPL + o] = col + 3; int s = atomicAdd(&upCnt[col + 3], 1); if (s < CAPL) upCols[(size_t)(col + 3) * CAPL + s] = row; } o++; }
        }
      }
      if (tid == 0) lowCnt[row] = total;
      __syncthreads();                     // wsum2 reuse for next half
    }
    return;
  }
  if (bx >= 394) {
    // ---- Hb: bf16 mirror of H ----
    int base = (bx - 394) * 8192;
#pragma unroll
    for (int q = 0; q < 8; ++q) {
      int idx = base + q * 1024 + tid * 4;
      float4 v = *(const float4*)(H + idx);
      uint2 p2;
      p2.x = (unsigned)f2bf(v.x) | ((unsigned)f2bf(v.y) << 16);
      p2.y = (unsigned)f2bf(v.z) | ((unsigned)f2bf(v.w) << 16);
      *(uint2*)(Hb + idx) = p2;
    }
    return;
  }
  if (bx >= 266) {
    // ---- B2 transpose: B2[p][d] = U[k][d][r] ----
    int idx = (bx - 266) * 256 + tid;
    int k = idx / (DD * RR);
    int rem = idx % (DD * RR);
    int d = rem / RR;
    int r = rem % RR;
    B2[(k * RR + r) * DD + d] = U[idx];
    return;
  }
  if (bx >= 256) {
    // ---- orth: reads U directly ----
    int bid = bx - 256;
    int b = bid, k = 0;
    while (b >= (KH - k)) { b -= (KH - k); k++; }
    int l = k + b;
    float* redo = smem;
    const float* uk = U + (size_t)k * DD * RR;
    const float* ul = U + (size_t)l * DD * RR;
    float acc = 0.f;
#pragma unroll
    for (int q = 0; q < 4; ++q) {
      int e = tid * 4 + q;
      int r = e >> 5, s2 = e & 31;
      float g = 0.f;
      for (int d = 0; d < DD; ++d) g += uk[d * RR + r] * ul[d * RR + s2];
      if (k == l) {
        float c3 = g - (r == s2 ? 1.f : 0.f);
        acc += c3 * c3;
      } else {
        acc += g * g;
      }
    }
    redo[tid] = acc;
    __syncthreads();
    for (int off = 128; off > 0; off >>= 1) {
      if (tid < off) redo[tid] += redo[tid + off];
      __syncthreads();
    }
    if (tid == 0) orth_part[bid] = redo[0];
    return;
  }
  // ---- Z-GEMM: Zb = bf16(H @ B1) ----
  float* As = smem;
  float* Bs = smem + 1056;
  int r0 = bx * 32;
  int tx = tid & 15, ty = tid >> 4;
  int cx = tx * 8, ry = ty * 2;
  float acc[2][8];
#pragma unroll
  for (int i = 0; i < 2; ++i)
#pragma unroll
    for (int j = 0; j < 8; ++j) acc[i][j] = 0.f;

  for (int k0 = 0; k0 < DD; k0 += 32) {
    {
      int r = tid >> 3;
      int kc = (tid & 7) * 4;
      float4 x = *(const float4*)(H + (size_t)(r0 + r) * DD + k0 + kc);
      As[(kc + 0) * 33 + r] = x.x; As[(kc + 1) * 33 + r] = x.y;
      As[(kc + 2) * 33 + r] = x.z; As[(kc + 3) * 33 + r] = x.w;
    }
#pragma unroll
    for (int q = 0; q < 4; ++q) {
      int f = tid + 256 * q;
      int kk = f >> 5, pc = (f & 31) * 4;
      *(float4*)(&Bs[kk * 128 + pc]) =
          *(const float4*)(U + (size_t)(pc >> 5) * DD * RR + (size_t)(k0 + kk) * RR + (pc & 31));
    }
    __syncthreads();
#pragma unroll
    for (int kk = 0; kk < 32; ++kk) {
      float av[2];
      av[0] = As[kk * 33 + ry]; av[1] = As[kk * 33 + ry + 1];
      float bv[8];
      *(float4*)(bv) = *(const float4*)(&Bs[kk * 128 + cx]);
      *(float4*)(bv + 4) = *(const float4*)(&Bs[kk * 128 + cx + 4]);
#pragma unroll
      for (int i = 0; i < 2; ++i)
#pragma unroll
        for (int j = 0; j < 8; ++j) acc[i][j] += av[i] * bv[j];
    }
    __syncthreads();
  }
#pragma unroll
  for (int i = 0; i < 2; ++i) {
    uint4 p;
    p.x = (unsigned)f2bf(acc[i][0]) | ((unsigned)f2bf(acc[i][1]) << 16);
    p.y = (unsigned)f2bf(acc[i][2]) | ((unsigned)f2bf(acc[i][3]) << 16);
    p.z = (unsigned)f2bf(acc[i][4]) | ((unsigned)f2bf(acc[i][5]) << 16);
    p.w = (unsigned)f2bf(acc[i][6]) | ((unsigned)f2bf(acc[i][7]) << 16);
    *(uint4*)(Zb + (size_t)(r0 + ry + i) * PP + cx) = p;
  }
}

// ======== K2: assemble CSR -> S-gather + attention (4-deep MLP unroll) ====================
__global__ __launch_bounds__(256) void csr_attn_s(const unsigned short* __restrict__ Zb,
                                                  const unsigned short* __restrict__ Hb,
                                                  const int* __restrict__ lowCols,
                                                  const int* __restrict__ lowCnt,
                                                  const int* __restrict__ upCols,
                                                  const int* __restrict__ upCnt,
                                                  float* __restrict__ dinv,
                                                  float* __restrict__ aggZ,
                                                  float* __restrict__ S) {
  int row = blockIdx.x;
  int tid = threadIdx.x;
  int lane = tid & 63, wv = tid >> 6;
  __shared__ int scols[CAP];
  __shared__ int utmp[CAPL];
  __shared__ float zi[PP];
  __shared__ unsigned short zzb[NSTASH][130];  // stride 65 words: conflict-free
  __shared__ float sdinv[CAP];
  __shared__ float uni[1024];  // union: sred f4[4][64] | alpha[4][128]+redp f2[4][64]

  // own Z row (bf16 -> f32)
  if (tid < PP) zi[tid] = bflo((unsigned)Zb[(size_t)row * PP + tid]);

  // ---- assemble neighbor list: lower ++ diag ++ rank-sorted upper (== dense-scan order) --
  int lcT = lowCnt[row];
  int ucT = upCnt[row];
  int lc = lcT < (CAP - 1) ? lcT : (CAP - 1);
  for (int t = tid; t < lc; t += 256) scols[t] = lowCols[(size_t)row * CAPL + t];
  if (tid == 0) scols[lc] = row;
  int ucR = ucT < CAPL ? ucT : CAPL;
  for (int t = tid; t < ucR; t += 256) utmp[t] = upCols[(size_t)row * CAPL + t];
  __syncthreads();
  for (int t = tid; t < ucR; t += 256) {
    int e = utmp[t], r = 0;
    for (int q = 0; q < ucR; ++q) r += (utmp[q] < e);   // distinct -> exact rank
    int pos = lc + 1 + r;
    if (pos < CAP) scols[pos] = e;
  }
  int total = lcT + 1 + ucT;
  int nn = total < CAP ? total : CAP;
  if (tid == 0) dinv[row] = 1.0f / sqrtf((float)total);
  __syncthreads();

  // per-neighbor dinv on the fly (lowCnt/upCnt are L2-hot 32KB arrays)
  if (tid < nn) {
    int c = scols[tid];
    int cc = lowCnt[c] + 1 + upCnt[c];
    sdinv[tid] = 1.0f / sqrtf((float)cc);
  }
  __syncthreads();

  // ---- phase 1: Zb stash + S gather over Hb; 4-deep unroll (jj..jj+12 in flight) ----
  {
    float4 a0 = make_float4(0.f, 0.f, 0.f, 0.f);
    float4 a1 = make_float4(0.f, 0.f, 0.f, 0.f);
    float4 a2 = make_float4(0.f, 0.f, 0.f, 0.f);
    float4 a3 = make_float4(0.f, 0.f, 0.f, 0.f);
    for (int jj = wv; jj < nn; jj += 16) {
      int j1 = jj + 4, j2 = jj + 8, j3 = jj + 12;
      bool b1 = j1 < nn, b2 = j2 < nn, b3 = j3 < nn;
      int c0 = scols[jj];
      int c1 = b1 ? scols[j1] : 0;
      int c2 = b2 ? scols[j2] : 0;
      int c3 = b3 ? scols[j3] : 0;
      uint2 u0 = *(const uint2*)(Hb + (size_t)c0 * DD + lane * 4);
      uint2 u1, u2, u3;
      if (b1) u1 = *(const uint2*)(Hb + (size_t)c1 * DD + lane * 4);
      if (b2) u2 = *(const uint2*)(Hb + (size_t)c2 * DD + lane * 4);
      if (b3) u3 = *(const uint2*)(Hb + (size_t)c3 * DD + lane * 4);
      if (jj < NSTASH) {
        unsigned x = *(const unsigned*)(Zb + (size_t)c0 * PP + lane * 2);
        *(unsigned*)(&zzb[jj][lane * 2]) = x;
      }
      if (b1 && j1 < NSTASH) {
        unsigned x = *(const unsigned*)(Zb + (size_t)c1 * PP + lane * 2);
        *(unsigned*)(&zzb[j1][lane * 2]) = x;
      }
      if (b2 && j2 < NSTASH) {
        unsigned x = *(const unsigned*)(Zb + (size_t)c2 * PP + lane * 2);
        *(unsigned*)(&zzb[j2][lane * 2]) = x;
      }
      if (b3 && j3 < NSTASH) {
        unsigned x = *(const unsigned*)(Zb + (size_t)c3 * PP + lane * 2);
        *(unsigned*)(&zzb[j3][lane * 2]) = x;
      }
      float w0 = sdinv[jj];
      a0.x += w0 * bflo(u0.x); a0.y += w0 * bfhi(u0.x);
      a0.z += w0 * bflo(u0.y); a0.w += w0 * bfhi(u0.y);
      if (b1) {
        float w1 = sdinv[j1];
        a1.x += w1 * bflo(u1.x); a1.y += w1 * bfhi(u1.x);
        a1.z += w1 * bflo(u1.y); a1.w += w1 * bfhi(u1.y);
      }
      if (b2) {
        float w2 = sdinv[j2];
        a2.x += w2 * bflo(u2.x); a2.y += w2 * bfhi(u2.x);
        a2.z += w2 * bflo(u2.y); a2.w += w2 * bfhi(u2.y);
      }
      if (b3) {
        float w3 = sdinv[j3];
        a3.x += w3 * bflo(u3.x); a3.y += w3 * bfhi(u3.x);
        a3.z += w3 * bflo(u3.y); a3.w += w3 * bfhi(u3.y);
      }
    }
    a0.x += a1.x + a2.x + a3.x;
    a0.y += a1.y + a2.y + a3.y;
    a0.z += a1.z + a2.z + a3.z;
    a0.w += a1.w + a2.w + a3.w;
    *(float4*)(&uni[wv * 256 + lane * 4]) = a0;   // sred[wv][lane]
  }
  __syncthreads();
  {
    float s = uni[0 * 256 + tid] + uni[1 * 256 + tid] + uni[2 * 256 + tid] + uni[3 * 256 + tid];
    S[(size_t)row * DD + tid] = s;
  }
  __syncthreads();   // sred dead; uni becomes alpha/redp

  // ---- phase 2: scores + wave-parallel softmax (wave wv = head wv) ----
  {
    int k = wv;
    float s0 = -1e30f, s1 = -1e30f;
    if (lane < nn) {
      float acc = 0.f;
      if (lane < NSTASH) {
        const unsigned short* zs = &zzb[lane][k * RR];
#pragma unroll
        for (int r = 0; r < RR; r += 4) {
          float4 aa = *(const float4*)(zi + k * RR + r);
          unsigned u0 = *(const unsigned*)(zs + r);
          unsigned u1 = *(const unsigned*)(zs + r + 2);
          acc += aa.x * bflo(u0) + aa.y * bfhi(u0) + aa.z * bflo(u1) + aa.w * bfhi(u1);
        }
      } else {
        const unsigned short* zj = Zb + (size_t)scols[lane] * PP + k * RR;
#pragma unroll
        for (int r = 0; r < RR; r += 4) {
          float4 aa = *(const float4*)(zi + k * RR + r);
          unsigned u0 = *(const unsigned*)(zj + r);
          unsigned u1 = *(const unsigned*)(zj + r + 2);
          acc += aa.x * bflo(u0) + aa.y * bfhi(u0) + aa.z * bflo(u1) + aa.w * bfhi(u1);
        }
      }
      s0 = acc * SCALE;
    }
    int j1 = lane + 64;
    if (j1 < nn) {
      const unsigned short* zj = Zb + (size_t)scols[j1] * PP + k * RR;
      float acc = 0.f;
#pragma unroll
      for (int r = 0; r < RR; r += 4) {
        float4 aa = *(const float4*)(zi + k * RR + r);
        unsigned u0 = *(const unsigned*)(zj + r);
        unsigned u1 = *(const unsigned*)(zj + r + 2);
        acc += aa.x * bflo(u0) + aa.y * bfhi(u0) + aa.z * bflo(u1) + aa.w * bfhi(u1);
      }
      s1 = acc * SCALE;
    }
    float m = fmaxf(s0, s1);
#pragma unroll
    for (int off = 32; off > 0; off >>= 1) m = fmaxf(m, __shfl_xor(m, off));
    float e0 = (lane < nn) ? expf(s0 - m) : 0.f;
    float e1 = (j1 < nn) ? expf(s1 - m) : 0.f;
    float s = e0 + e1;
#pragma unroll
    for (int off = 32; off > 0; off >>= 1) s += __shfl_xor(s, off);
    float inv = 1.0f / s;
    if (lane < nn) uni[k * CAP + lane] = e0 * inv;        // alpha[k][lane]
    if (j1 < nn) uni[k * CAP + j1] = e1 * inv;
  }
  __syncthreads();

  // ---- phase 3: aggZ = sum_j alpha*zz; thread owns col-pair, 4-way jj split ----
  {
    int c2 = tid & 63, hf = tid >> 6;
    int hd = c2 >> 4;
    float a0 = 0.f, a1 = 0.f;
    for (int jj = hf; jj < nn; jj += 4) {
      unsigned u;
      if (jj < NSTASH) u = *(const unsigned*)(&zzb[jj][c2 * 2]);
      else u = *(const unsigned*)(Zb + (size_t)scols[jj] * PP + c2 * 2);
      float al = uni[hd * CAP + jj];
      a0 += al * bflo(u);
      a1 += al * bfhi(u);
    }
    *(float2*)(&uni[512 + hf * 128 + c2 * 2]) = make_float2(a0, a1);   // redp[hf][c2]
  }
  __syncthreads();
  if (tid < 64) {
    float2 r0 = *(float2*)(&uni[512 + 0 * 128 + tid * 2]);
    float2 r1 = *(float2*)(&uni[512 + 1 * 128 + tid * 2]);
    float2 r2 = *(float2*)(&uni[512 + 2 * 128 + tid * 2]);
    float2 r3 = *(float2*)(&uni[512 + 3 * 128 + tid * 2]);
    float2 s2 = make_float2(r0.x + r1.x + r2.x + r3.x, r0.y + r1.y + r2.y + r3.y);
    *(float2*)(aggZ + (size_t)row * PP + tid * 2) = s2;
  }
}

// ======== K3: epilogue GEMM + Laplacian + soft-threshold; writes out f32 + Houtb bf16 =====
__global__ __launch_bounds__(256) void egemm(const float* __restrict__ A,   // aggZ [N][128]
                                             const float* __restrict__ B,   // B2 [128][256]
                                             const float* __restrict__ Hm,
                                             const float* __restrict__ S,
                                             const float* __restrict__ dinv,
                                             const float* __restrict__ thr,
                                             const float* __restrict__ lambda_p,
                                             float* __restrict__ out,
                                             unsigned short* __restrict__ Houtb) {
  __shared__ float As[32][33];
  __shared__ float Bs[32][128];
  int tid = threadIdx.x;
  int r0 = blockIdx.x * 32;
  int c0 = blockIdx.y * 128;
  int tx = tid & 15, ty = tid >> 4;
  int cx = tx * 8, ry = ty * 2;
  float acc[2][8];
#pragma unroll
  for (int i = 0; i < 2; ++i)
#pragma unroll
    for (int j = 0; j < 8; ++j) acc[i][j] = 0.f;

  for (int k0 = 0; k0 < PP; k0 += 32) {
    {
      int r = tid >> 3;
      int kc = (tid & 7) * 4;
      float4 x = *(const float4*)(A + (size_t)(r0 + r) * PP + k0 + kc);
      As[kc + 0][r] = x.x; As[kc + 1][r] = x.y; As[kc + 2][r] = x.z; As[kc + 3][r] = x.w;
    }
#pragma unroll
    for (int q = 0; q < 4; ++q) {
      int f = tid + 256 * q;
      int kk = f >> 5, pc = (f & 31) * 4;
      *(float4*)(&Bs[kk][pc]) = *(const float4*)(B + (size_t)(k0 + kk) * DD + c0 + pc);
    }
    __syncthreads();
#pragma unroll
    for (int kk = 0; kk < 32; ++kk) {
      float av[2];
      av[0] = As[kk][ry]; av[1] = As[kk][ry + 1];
      float bv[8];
      *(float4*)(bv) = *(const float4*)(&Bs[kk][cx]);
      *(float4*)(bv + 4) = *(const float4*)(&Bs[kk][cx + 4]);
#pragma unroll
      for (int i = 0; i < 2; ++i)
#pragma unroll
        for (int j = 0; j < 8; ++j) acc[i][j] += av[i] * bv[j];
    }
    __syncthreads();
  }
  float lam = lambda_p[0];
  int gc = c0 + cx;
  float4 t0 = *(const float4*)(thr + gc);
  float4 t1 = *(const float4*)(thr + gc + 4);
#pragma unroll
  for (int i = 0; i < 2; ++i) {
    int gr = r0 + ry + i;
    float dv = dinv[gr];
    float4 h0 = *(const float4*)(Hm + (size_t)gr * DD + gc);
    float4 h1 = *(const float4*)(Hm + (size_t)gr * DD + gc + 4);
    float4 s0 = *(const float4*)(S + (size_t)gr * DD + gc);
    float4 s1 = *(const float4*)(S + (size_t)gr * DD + gc + 4);
    float hv[8] = {h0.x, h0.y, h0.z, h0.w, h1.x, h1.y, h1.z, h1.w};
    float sv[8] = {s0.x, s0.y, s0.z, s0.w, s1.x, s1.y, s1.z, s1.w};
    float tv[8] = {t0.x, t0.y, t0.z, t0.w, t1.x, t1.y, t1.z, t1.w};
    float ov[8];
#pragma unroll
    for (int j = 0; j < 8; ++j) {
      float val = hv[j] + ETA * acc[i][j] - ETA * lam * (hv[j] - dv * sv[j]);
      float av = fabsf(val) - tv[j];
      ov[j] = (av > 0.f) ? copysignf(av, val) : 0.f;
    }
    *(float4*)(out + (size_t)gr * DD + gc) = make_float4(ov[0], ov[1], ov[2], ov[3]);
    *(float4*)(out + (size_t)gr * DD + gc + 4) = make_float4(ov[4], ov[5], ov[6], ov[7]);
    uint4 p;
    p.x = (unsigned)f2bf(ov[0]) | ((unsigned)f2bf(ov[1]) << 16);
    p.y = (unsigned)f2bf(ov[2]) | ((unsigned)f2bf(ov[3]) << 16);
    p.z = (unsigned)f2bf(ov[4]) | ((unsigned)f2bf(ov[5]) << 16);
    p.w = (unsigned)f2bf(ov[6]) | ((unsigned)f2bf(ov[7]) << 16);
    *(uint4*)(Houtb + (size_t)gr * DD + gc) = p;
  }
}

// ======== K4: lap_smooth via lower edges only (4-deep MLP unroll) =========================
// lap = sum_i ||h_i||^2 (1 - dinv_i^2) - sum_{lower edges (i,j)} 2 dinv_i dinv_j <h_i,h_j>
__global__ __launch_bounds__(256) void lap_rows(const float* __restrict__ Hout,
                                                const unsigned short* __restrict__ Houtb,
                                                const int* __restrict__ lowCols,
                                                const int* __restrict__ lowCnt,
                                                const float* __restrict__ dinv,
                                                float* __restrict__ part) {
  int row = (NN - 1) - blockIdx.x;   // heavy rows first
  int tid = threadIdx.x;
  int lane = tid & 63, wv = tid >> 6;
  __shared__ int scols[CAPL];
  __shared__ float sdinv[CAPL];
  __shared__ float sred[4][260];
  int lcT = lowCnt[row];
  int lc = lcT < CAPL ? lcT : CAPL;
  if (tid < lc) {
    int c = lowCols[(size_t)row * CAPL + tid];
    scols[tid] = c;
    sdinv[tid] = 2.0f * dinv[c];
  }
  __syncthreads();
  float4 a0 = make_float4(0.f, 0.f, 0.f, 0.f);
  float4 a1 = make_float4(0.f, 0.f, 0.f, 0.f);
  float4 a2 = make_float4(0.f, 0.f, 0.f, 0.f);
  float4 a3 = make_float4(0.f, 0.f, 0.f, 0.f);
  for (int jj = wv; jj < lc; jj += 16) {
    int j1 = jj + 4, j2 = jj + 8, j3 = jj + 12;
    bool b1 = j1 < lc, b2 = j2 < lc, b3 = j3 < lc;
    uint2 u0 = *(const uint2*)(Houtb + (size_t)scols[jj] * DD + lane * 4);
    uint2 u1, u2, u3;
    if (b1) u1 = *(const uint2*)(Houtb + (size_t)scols[j1] * DD + lane * 4);
    if (b2) u2 = *(const uint2*)(Houtb + (size_t)scols[j2] * DD + lane * 4);
    if (b3) u3 = *(const uint2*)(Houtb + (size_t)scols[j3] * DD + lane * 4);
    float w0 = sdinv[jj];
    a0.x += w0 * bflo(u0.x); a0.y += w0 * bfhi(u0.x);
    a0.z += w0 * bflo(u0.y); a0.w += w0 * bfhi(u0.y);
    if (b1) {
      float w1 = sdinv[j1];
      a1.x += w1 * bflo(u1.x); a1.y += w1 * bfhi(u1.x);
      a1.z += w1 * bflo(u1.y); a1.w += w1 * bfhi(u1.y);
    }
    if (b2) {
      float w2 = sdinv[j2];
      a2.x += w2 * bflo(u2.x); a2.y += w2 * bfhi(u2.x);
      a2.z += w2 * bflo(u2.y); a2.w += w2 * bfhi(u2.y);
    }
    if (b3) {
      float w3 = sdinv[j3];
      a3.x += w3 * bflo(u3.x); a3.y += w3 * bfhi(u3.x);
      a3.z += w3 * bflo(u3.y); a3.w += w3 * bfhi(u3.y);
    }
  }
  a0.x += a1.x + a2.x + a3.x;
  a0.y += a1.y + a2.y + a3.y;
  a0.z += a1.z + a2.z + a3.z;
  a0.w += a1.w + a2.w + a3.w;
  *(float4*)(&sred[wv][lane * 4]) = a0;
  __syncthreads();
  if (wv == 0) {
    float4 s4;
    s4.x = sred[0][lane * 4 + 0] + sred[1][lane * 4 + 0] + sred[2][lane * 4 + 0] + sred[3][lane * 4 + 0];
    s4.y = sred[0][lane * 4 + 1] + sred[1][lane * 4 + 1] + sred[2][lane * 4 + 1] + sred[3][lane * 4 + 1];
    s4.z = sred[0][lane * 4 + 2] + sred[1][lane * 4 + 2] + sred[2][lane * 4 + 2] + sred[3][lane * 4 + 2];
    s4.w = sred[0][lane * 4 + 3] + sred[1][lane * 4 + 3] + sred[2][lane * 4 + 3] + sred[3][lane * 4 + 3];
    float4 h4 = *(const float4*)(Hout + (size_t)row * DD + lane * 4);
    float dvr = dinv[row];
    float own = 1.0f - dvr * dvr;
    float val = h4.x * (own * h4.x - dvr * s4.x) + h4.y * (own * h4.y - dvr * s4.y) +
                h4.z * (own * h4.z - dvr * s4.z) + h4.w * (own * h4.w - dvr * s4.w);
#pragma unroll
    for (int off = 32; off > 0; off >>= 1) val += __shfl_xor(val, off);
    if (lane == 0) part[row] = val;
  }
}

// ======== K5: deterministic final reduction ==============================================
__global__ __launch_bounds__(256) void finalize(const float* __restrict__ lap_part,
                                                const float* __restrict__ orth_part,
                                                float* __restrict__ out) {
  __shared__ double red[256];
  int tid = threadIdx.x;
  double s = 0.0;
  for (int i = tid; i < NN; i += 256) s += (double)lap_part[i];
  red[tid] = s;
  __syncthreads();
  for (int off = 128; off > 0; off >>= 1) {
    if (tid < off) red[tid] += red[tid + off];
    __syncthreads();
  }
  if (tid == 0) {
    double o = 0.0;
    for (int i = 0; i < 10; ++i) o += (double)orth_part[i];
    out[(size_t)NN * DD] = (float)o;
    out[(size_t)NN * DD + 1] = (float)red[0];
  }
}

extern "C" void kernel_launch(void* const* d_in, const int* in_sizes, int n_in,
                              void* d_out, int out_size, void* d_ws, size_t ws_size,
                              hipStream_t stream) {
  const float* H = (const float*)d_in[0];
  const float* A = (const float*)d_in[1];
  // d_in[2] (dense L) intentionally unused: L reconstructed exactly from A.
  const float* U = (const float*)d_in[3];
  const float* lambda_p = (const float*)d_in[4];
  const float* thr = (const float*)d_in[5];
  float* out = (float*)d_out;

  char* w = (char*)d_ws;
  float* B2 = (float*)w;             w += (size_t)PP * DD * 4;     // 128 KB
  int* lowCols = (int*)w;            w += (size_t)NN * CAPL * 4;   // 4 MB
  int* upCols = (int*)w;             w += (size_t)NN * CAPL * 4;   // 4 MB
  int* lowCnt = (int*)w;             w += (size_t)NN * 4;
  int* upCnt = (int*)w;              w += (size_t)NN * 4;
  float* dinv = (float*)w;           w += (size_t)NN * 4;
  unsigned short* Zb = (unsigned short*)w;   w += (size_t)NN * PP * 2;   // 2 MB
  unsigned short* Hb = (unsigned short*)w;   w += (size_t)NN * DD * 2;   // 4 MB
  unsigned short* Houtb = (unsigned short*)w; w += (size_t)NN * DD * 2;  // 4 MB
  float* aggZ = (float*)w;           w += (size_t)NN * PP * 4;     // 4 MB
  float* S = (float*)w;              w += (size_t)NN * DD * 4;     // 8 MB
  float* lap_part = (float*)w;       w += (size_t)NN * 4;
  float* orth_part = (float*)w;      w += 64;

  hipMemsetAsync(upCnt, 0, (size_t)NN * 4, stream);   // graph-capturable
  zgemm_scan<<<dim3(650 + NN / 2), dim3(256), 0, stream>>>(A, H, U, B2, Zb, Hb, orth_part,
                                                           lowCols, lowCnt, upCols, upCnt);
  csr_attn_s<<<dim3(NN), dim3(256), 0, stream>>>(Zb, Hb, lowCols, lowCnt, upCols, upCnt,
                                                 dinv, aggZ, S);
  egemm<<<dim3(NN / 32, 2), dim3(256), 0, stream>>>(aggZ, B2, H, S, dinv, thr, lambda_p,
                                                    out, Houtb);
  lap_rows<<<dim3(NN), dim3(256), 0, stream>>>(out, Houtb, lowCols, lowCnt, dinv, lap_part);
  finalize<<<dim3(1), dim3(256), 0, stream>>>(lap_part, orth_part, out);
}

// Round 15
// 144.407 us; speedup vs baseline: 1.1324x; 1.1324x over previous
//
#include <hip/hip_runtime.h>
#include <hip/hip_bf16.h>
#include <math.h>

#define NN 8192
#define DD 256
#define RR 32
#define KH 4
#define PP 128      // KH*RR
#define CAP 128     // max neighbors per row (mean ~34)
#define CAPL 128    // per-row capacity of lower/upper half-lists
#define NSTASH 48   // neighbors stashed in LDS (global fallback above)
#define ETA 0.5f
#define SCALE 0.17677669529663687f  // 1/sqrt(32)

// bf16 helpers (explicit bit ops: deterministic)
__device__ __forceinline__ unsigned short f2bf(float f) {
  union { float f; unsigned u; } v; v.f = f;
  unsigned r = v.u + 0x7fffu + ((v.u >> 16) & 1u);   // round-to-nearest-even
  return (unsigned short)(r >> 16);
}
__device__ __forceinline__ float bflo(unsigned u) { return __uint_as_float(u << 16); }
__device__ __forceinline__ float bfhi(unsigned u) { return __uint_as_float(u & 0xffff0000u); }

// ======== K1: Z-GEMM (0..255) | orth (256..265) | B2 (266..393) | Hb (394..649)
//              | paired lower-triangle A-scan (650..4745): rows {NN-1-p, p}, 9 chunks/block
__global__ __launch_bounds__(256) void zgemm_scan(const float* __restrict__ A,
                                                  const float* __restrict__ H,
                                                  const float* __restrict__ U,
                                                  float* __restrict__ B2,
                                                  unsigned short* __restrict__ Zb,
                                                  unsigned short* __restrict__ Hb,
                                                  float* __restrict__ orth_part,
                                                  int* __restrict__ lowCols,
                                                  int* __restrict__ lowCnt,
                                                  int* __restrict__ upCols,
                                                  int* __restrict__ upCnt) {
  __shared__ float smem[5152];
  int tid = threadIdx.x;
  int bx = blockIdx.x;
  int lane = tid & 63, wv = tid >> 6;

  if (bx >= 650) {
    // ---- paired symmetric scan: strict-lower triangle, R13 chunk structure verbatim ----
    int p = bx - 650;                      // 0..4095
    __shared__ int wsum2[4];
    __shared__ int sbase;
#pragma unroll
    for (int half = 0; half < 2; ++half) {
      int row = (half == 0) ? (NN - 1 - p) : p;
      const float* a = A + (size_t)row * NN;
      if (tid == 0) sbase = 0;
      int nch = (row >> 10) + 1;
      for (int c = 0; c < nch; ++c) {
        int g0 = c * 1024 + tid * 4;
        float4 x = *(const float4*)(a + g0);
        int m0 = (g0 + 0 < row) && (x.x != 0.f);
        int m1 = (g0 + 1 < row) && (x.y != 0.f);
        int m2 = (g0 + 2 < row) && (x.z != 0.f);
        int m3 = (g0 + 3 < row) && (x.w != 0.f);
        int cnt = m0 + m1 + m2 + m3;
        int incl = cnt;
#pragma unroll
        for (int off = 1; off < 64; off <<= 1) {
          int t = __shfl_up(incl, off);
          if (lane >= off) incl += t;
        }
        if (lane == 63) wsum2[wv] = incl;
        __syncthreads();
        int base = sbase;
#pragma unroll
        for (int w = 0; w < 4; ++w) if (w < wv) base += wsum2[w];
        int o = base + incl - cnt;
        int chunkTot = wsum2[0] + wsum2[1] + wsum2[2] + wsum2[3];
        if (m0) { int col = g0 + 0; if (o < CAPL) { lowCols[(size_t)row * CAPL + o] = col; int s = atomicAdd(&upCnt[col], 1); if (s < CAPL) upCols[(size_t)col * CAPL + s] = row; } o++; }
        if (m1) { int col = g0 + 1; if (o < CAPL) { lowCols[(size_t)row * CAPL + o] = col; int s = atomicAdd(&upCnt[col], 1); if (s < CAPL) upCols[(size_t)col * CAPL + s] = row; } o++; }
        if (m2) { int col = g0 + 2; if (o < CAPL) { lowCols[(size_t)row * CAPL + o] = col; int s = atomicAdd(&upCnt[col], 1); if (s < CAPL) upCols[(size_t)col * CAPL + s] = row; } o++; }
        if (m3) { int col = g0 + 3; if (o < CAPL) { lowCols[(size_t)row * CAPL + o] = col; int s = atomicAdd(&upCnt[col], 1); if (s < CAPL) upCols[(size_t)col * CAPL + s] = row; } o++; }
        __syncthreads();
        if (tid == 0) sbase = base + chunkTot;
      }
      __syncthreads();
      if (tid == 0) lowCnt[row] = sbase;
      __syncthreads();                     // wsum2/sbase safe for next half
    }
    return;
  }
  if (bx >= 394) {
    // ---- Hb: bf16 mirror of H ----
    int base = (bx - 394) * 8192;
#pragma unroll
    for (int q = 0; q < 8; ++q) {
      int idx = base + q * 1024 + tid * 4;
      float4 v = *(const float4*)(H + idx);
      uint2 p2;
      p2.x = (unsigned)f2bf(v.x) | ((unsigned)f2bf(v.y) << 16);
      p2.y = (unsigned)f2bf(v.z) | ((unsigned)f2bf(v.w) << 16);
      *(uint2*)(Hb + idx) = p2;
    }
    return;
  }
  if (bx >= 266) {
    // ---- B2 transpose: B2[p][d] = U[k][d][r] ----
    int idx = (bx - 266) * 256 + tid;
    int k = idx / (DD * RR);
    int rem = idx % (DD * RR);
    int d = rem / RR;
    int r = rem % RR;
    B2[(k * RR + r) * DD + d] = U[idx];
    return;
  }
  if (bx >= 256) {
    // ---- orth: reads U directly ----
    int bid = bx - 256;
    int b = bid, k = 0;
    while (b >= (KH - k)) { b -= (KH - k); k++; }
    int l = k + b;
    float* redo = smem;
    const float* uk = U + (size_t)k * DD * RR;
    const float* ul = U + (size_t)l * DD * RR;
    float acc = 0.f;
#pragma unroll
    for (int q = 0; q < 4; ++q) {
      int e = tid * 4 + q;
      int r = e >> 5, s2 = e & 31;
      float g = 0.f;
      for (int d = 0; d < DD; ++d) g += uk[d * RR + r] * ul[d * RR + s2];
      if (k == l) {
        float c3 = g - (r == s2 ? 1.f : 0.f);
        acc += c3 * c3;
      } else {
        acc += g * g;
      }
    }
    redo[tid] = acc;
    __syncthreads();
    for (int off = 128; off > 0; off >>= 1) {
      if (tid < off) redo[tid] += redo[tid + off];
      __syncthreads();
    }
    if (tid == 0) orth_part[bid] = redo[0];
    return;
  }
  // ---- Z-GEMM: Zb = bf16(H @ B1) ----
  float* As = smem;
  float* Bs = smem + 1056;
  int r0 = bx * 32;
  int tx = tid & 15, ty = tid >> 4;
  int cx = tx * 8, ry = ty * 2;
  float acc[2][8];
#pragma unroll
  for (int i = 0; i < 2; ++i)
#pragma unroll
    for (int j = 0; j < 8; ++j) acc[i][j] = 0.f;

  for (int k0 = 0; k0 < DD; k0 += 32) {
    {
      int r = tid >> 3;
      int kc = (tid & 7) * 4;
      float4 x = *(const float4*)(H + (size_t)(r0 + r) * DD + k0 + kc);
      As[(kc + 0) * 33 + r] = x.x; As[(kc + 1) * 33 + r] = x.y;
      As[(kc + 2) * 33 + r] = x.z; As[(kc + 3) * 33 + r] = x.w;
    }
#pragma unroll
    for (int q = 0; q < 4; ++q) {
      int f = tid + 256 * q;
      int kk = f >> 5, pc = (f & 31) * 4;
      *(float4*)(&Bs[kk * 128 + pc]) =
          *(const float4*)(U + (size_t)(pc >> 5) * DD * RR + (size_t)(k0 + kk) * RR + (pc & 31));
    }
    __syncthreads();
#pragma unroll
    for (int kk = 0; kk < 32; ++kk) {
      float av[2];
      av[0] = As[kk * 33 + ry]; av[1] = As[kk * 33 + ry + 1];
      float bv[8];
      *(float4*)(bv) = *(const float4*)(&Bs[kk * 128 + cx]);
      *(float4*)(bv + 4) = *(const float4*)(&Bs[kk * 128 + cx + 4]);
#pragma unroll
      for (int i = 0; i < 2; ++i)
#pragma unroll
        for (int j = 0; j < 8; ++j) acc[i][j] += av[i] * bv[j];
    }
    __syncthreads();
  }
#pragma unroll
  for (int i = 0; i < 2; ++i) {
    uint4 p;
    p.x = (unsigned)f2bf(acc[i][0]) | ((unsigned)f2bf(acc[i][1]) << 16);
    p.y = (unsigned)f2bf(acc[i][2]) | ((unsigned)f2bf(acc[i][3]) << 16);
    p.z = (unsigned)f2bf(acc[i][4]) | ((unsigned)f2bf(acc[i][5]) << 16);
    p.w = (unsigned)f2bf(acc[i][6]) | ((unsigned)f2bf(acc[i][7]) << 16);
    *(uint4*)(Zb + (size_t)(r0 + ry + i) * PP + cx) = p;
  }
}

// ======== K2: assemble CSR -> S-gather + attention (merged; 2-deep MLP unroll) ============
__global__ __launch_bounds__(256) void csr_attn_s(const unsigned short* __restrict__ Zb,
                                                  const unsigned short* __restrict__ Hb,
                                                  const int* __restrict__ lowCols,
                                                  const int* __restrict__ lowCnt,
                                                  const int* __restrict__ upCols,
                                                  const int* __restrict__ upCnt,
                                                  float* __restrict__ dinv,
                                                  float* __restrict__ aggZ,
                                                  float* __restrict__ S) {
  int row = blockIdx.x;
  int tid = threadIdx.x;
  int lane = tid & 63, wv = tid >> 6;
  __shared__ int scols[CAP];
  __shared__ int utmp[CAPL];
  __shared__ float zi[PP];
  __shared__ unsigned short zzb[NSTASH][130];  // stride 65 words: conflict-free
  __shared__ float sdinv[CAP];
  __shared__ float uni[1024];  // union: sred f4[4][64] | alpha[4][128]+redp f2[4][64]

  // own Z row (bf16 -> f32)
  if (tid < PP) zi[tid] = bflo((unsigned)Zb[(size_t)row * PP + tid]);

  // ---- assemble neighbor list: lower ++ diag ++ rank-sorted upper (== dense-scan order) --
  int lcT = lowCnt[row];
  int ucT = upCnt[row];
  int lc = lcT < (CAP - 1) ? lcT : (CAP - 1);
  for (int t = tid; t < lc; t += 256) scols[t] = lowCols[(size_t)row * CAPL + t];
  if (tid == 0) scols[lc] = row;
  int ucR = ucT < CAPL ? ucT : CAPL;
  for (int t = tid; t < ucR; t += 256) utmp[t] = upCols[(size_t)row * CAPL + t];
  __syncthreads();
  for (int t = tid; t < ucR; t += 256) {
    int e = utmp[t], r = 0;
    for (int q = 0; q < ucR; ++q) r += (utmp[q] < e);   // distinct -> exact rank
    int pos = lc + 1 + r;
    if (pos < CAP) scols[pos] = e;
  }
  int total = lcT + 1 + ucT;
  int nn = total < CAP ? total : CAP;
  if (tid == 0) dinv[row] = 1.0f / sqrtf((float)total);
  __syncthreads();

  // per-neighbor dinv on the fly (lowCnt/upCnt are L2-hot 32KB arrays)
  if (tid < nn) {
    int c = scols[tid];
    int cc = lowCnt[c] + 1 + upCnt[c];
    sdinv[tid] = 1.0f / sqrtf((float)cc);
  }
  __syncthreads();

  // ---- phase 1: Zb stash + S gather over Hb; 2-deep unroll (jj, jj+4 in flight) ----
  {
    float4 accA = make_float4(0.f, 0.f, 0.f, 0.f);
    float4 accB = make_float4(0.f, 0.f, 0.f, 0.f);
    for (int jj = wv; jj < nn; jj += 8) {
      int jB = jj + 4;
      int cA = scols[jj];
      uint2 uA = *(const uint2*)(Hb + (size_t)cA * DD + lane * 4);
      if (jB < nn) {
        int cB = scols[jB];
        uint2 uB = *(const uint2*)(Hb + (size_t)cB * DD + lane * 4);
        if (jB < NSTASH) {
          unsigned xB = *(const unsigned*)(Zb + (size_t)cB * PP + lane * 2);
          *(unsigned*)(&zzb[jB][lane * 2]) = xB;
        }
        float wB = sdinv[jB];
        accB.x += wB * bflo(uB.x); accB.y += wB * bfhi(uB.x);
        accB.z += wB * bflo(uB.y); accB.w += wB * bfhi(uB.y);
      }
      if (jj < NSTASH) {
        unsigned xA = *(const unsigned*)(Zb + (size_t)cA * PP + lane * 2);
        *(unsigned*)(&zzb[jj][lane * 2]) = xA;
      }
      float wA = sdinv[jj];
      accA.x += wA * bflo(uA.x); accA.y += wA * bfhi(uA.x);
      accA.z += wA * bflo(uA.y); accA.w += wA * bfhi(uA.y);
    }
    accA.x += accB.x; accA.y += accB.y; accA.z += accB.z; accA.w += accB.w;
    *(float4*)(&uni[wv * 256 + lane * 4]) = accA;   // sred[wv][lane]
  }
  __syncthreads();
  {
    float s = uni[0 * 256 + tid] + uni[1 * 256 + tid] + uni[2 * 256 + tid] + uni[3 * 256 + tid];
    S[(size_t)row * DD + tid] = s;
  }
  __syncthreads();   // sred dead; uni becomes alpha/redp

  // ---- phase 2: scores + wave-parallel softmax (wave wv = head wv) ----
  {
    int k = wv;
    float s0 = -1e30f, s1 = -1e30f;
    if (lane < nn) {
      float acc = 0.f;
      if (lane < NSTASH) {
        const unsigned short* zs = &zzb[lane][k * RR];
#pragma unroll
        for (int r = 0; r < RR; r += 4) {
          float4 aa = *(const float4*)(zi + k * RR + r);
          unsigned u0 = *(const unsigned*)(zs + r);
          unsigned u1 = *(const unsigned*)(zs + r + 2);
          acc += aa.x * bflo(u0) + aa.y * bfhi(u0) + aa.z * bflo(u1) + aa.w * bfhi(u1);
        }
      } else {
        const unsigned short* zj = Zb + (size_t)scols[lane] * PP + k * RR;
#pragma unroll
        for (int r = 0; r < RR; r += 4) {
          float4 aa = *(const float4*)(zi + k * RR + r);
          unsigned u0 = *(const unsigned*)(zj + r);
          unsigned u1 = *(const unsigned*)(zj + r + 2);
          acc += aa.x * bflo(u0) + aa.y * bfhi(u0) + aa.z * bflo(u1) + aa.w * bfhi(u1);
        }
      }
      s0 = acc * SCALE;
    }
    int j1 = lane + 64;
    if (j1 < nn) {
      const unsigned short* zj = Zb + (size_t)scols[j1] * PP + k * RR;
      float acc = 0.f;
#pragma unroll
      for (int r = 0; r < RR; r += 4) {
        float4 aa = *(const float4*)(zi + k * RR + r);
        unsigned u0 = *(const unsigned*)(zj + r);
        unsigned u1 = *(const unsigned*)(zj + r + 2);
        acc += aa.x * bflo(u0) + aa.y * bfhi(u0) + aa.z * bflo(u1) + aa.w * bfhi(u1);
      }
      s1 = acc * SCALE;
    }
    float m = fmaxf(s0, s1);
#pragma unroll
    for (int off = 32; off > 0; off >>= 1) m = fmaxf(m, __shfl_xor(m, off));
    float e0 = (lane < nn) ? expf(s0 - m) : 0.f;
    float e1 = (j1 < nn) ? expf(s1 - m) : 0.f;
    float s = e0 + e1;
#pragma unroll
    for (int off = 32; off > 0; off >>= 1) s += __shfl_xor(s, off);
    float inv = 1.0f / s;
    if (lane < nn) uni[k * CAP + lane] = e0 * inv;        // alpha[k][lane]
    if (j1 < nn) uni[k * CAP + j1] = e1 * inv;
  }
  __syncthreads();

  // ---- phase 3: aggZ = sum_j alpha*zz; thread owns col-pair, 4-way jj split ----
  {
    int c2 = tid & 63, hf = tid >> 6;
    int hd = c2 >> 4;
    float a0 = 0.f, a1 = 0.f;
    for (int jj = hf; jj < nn; jj += 4) {
      unsigned u;
      if (jj < NSTASH) u = *(const unsigned*)(&zzb[jj][c2 * 2]);
      else u = *(const unsigned*)(Zb + (size_t)scols[jj] * PP + c2 * 2);
      float al = uni[hd * CAP + jj];
      a0 += al * bflo(u);
      a1 += al * bfhi(u);
    }
    *(float2*)(&uni[512 + hf * 128 + c2 * 2]) = make_float2(a0, a1);   // redp[hf][c2]
  }
  __syncthreads();
  if (tid < 64) {
    float2 r0 = *(float2*)(&uni[512 + 0 * 128 + tid * 2]);
    float2 r1 = *(float2*)(&uni[512 + 1 * 128 + tid * 2]);
    float2 r2 = *(float2*)(&uni[512 + 2 * 128 + tid * 2]);
    float2 r3 = *(float2*)(&uni[512 + 3 * 128 + tid * 2]);
    float2 s2 = make_float2(r0.x + r1.x + r2.x + r3.x, r0.y + r1.y + r2.y + r3.y);
    *(float2*)(aggZ + (size_t)row * PP + tid * 2) = s2;
  }
}

// ======== K3: epilogue GEMM + Laplacian + soft-threshold; writes out f32 + Houtb bf16 =====
__global__ __launch_bounds__(256) void egemm(const float* __restrict__ A,   // aggZ [N][128]
                                             const float* __restrict__ B,   // B2 [128][256]
                                             const float* __restrict__ Hm,
                                             const float* __restrict__ S,
                                             const float* __restrict__ dinv,
                                             const float* __restrict__ thr,
                                             const float* __restrict__ lambda_p,
                                             float* __restrict__ out,
                                             unsigned short* __restrict__ Houtb) {
  __shared__ float As[32][33];
  __shared__ float Bs[32][128];
  int tid = threadIdx.x;
  int r0 = blockIdx.x * 32;
  int c0 = blockIdx.y * 128;
  int tx = tid & 15, ty = tid >> 4;
  int cx = tx * 8, ry = ty * 2;
  float acc[2][8];
#pragma unroll
  for (int i = 0; i < 2; ++i)
#pragma unroll
    for (int j = 0; j < 8; ++j) acc[i][j] = 0.f;

  for (int k0 = 0; k0 < PP; k0 += 32) {
    {
      int r = tid >> 3;
      int kc = (tid & 7) * 4;
      float4 x = *(const float4*)(A + (size_t)(r0 + r) * PP + k0 + kc);
      As[kc + 0][r] = x.x; As[kc + 1][r] = x.y; As[kc + 2][r] = x.z; As[kc + 3][r] = x.w;
    }
#pragma unroll
    for (int q = 0; q < 4; ++q) {
      int f = tid + 256 * q;
      int kk = f >> 5, pc = (f & 31) * 4;
      *(float4*)(&Bs[kk][pc]) = *(const float4*)(B + (size_t)(k0 + kk) * DD + c0 + pc);
    }
    __syncthreads();
#pragma unroll
    for (int kk = 0; kk < 32; ++kk) {
      float av[2];
      av[0] = As[kk][ry]; av[1] = As[kk][ry + 1];
      float bv[8];
      *(float4*)(bv) = *(const float4*)(&Bs[kk][cx]);
      *(float4*)(bv + 4) = *(const float4*)(&Bs[kk][cx + 4]);
#pragma unroll
      for (int i = 0; i < 2; ++i)
#pragma unroll
        for (int j = 0; j < 8; ++j) acc[i][j] += av[i] * bv[j];
    }
    __syncthreads();
  }
  float lam = lambda_p[0];
  int gc = c0 + cx;
  float4 t0 = *(const float4*)(thr + gc);
  float4 t1 = *(const float4*)(thr + gc + 4);
#pragma unroll
  for (int i = 0; i < 2; ++i) {
    int gr = r0 + ry + i;
    float dv = dinv[gr];
    float4 h0 = *(const float4*)(Hm + (size_t)gr * DD + gc);
    float4 h1 = *(const float4*)(Hm + (size_t)gr * DD + gc + 4);
    float4 s0 = *(const float4*)(S + (size_t)gr * DD + gc);
    float4 s1 = *(const float4*)(S + (size_t)gr * DD + gc + 4);
    float hv[8] = {h0.x, h0.y, h0.z, h0.w, h1.x, h1.y, h1.z, h1.w};
    float sv[8] = {s0.x, s0.y, s0.z, s0.w, s1.x, s1.y, s1.z, s1.w};
    float tv[8] = {t0.x, t0.y, t0.z, t0.w, t1.x, t1.y, t1.z, t1.w};
    float ov[8];
#pragma unroll
    for (int j = 0; j < 8; ++j) {
      float val = hv[j] + ETA * acc[i][j] - ETA * lam * (hv[j] - dv * sv[j]);
      float av = fabsf(val) - tv[j];
      ov[j] = (av > 0.f) ? copysignf(av, val) : 0.f;
    }
    *(float4*)(out + (size_t)gr * DD + gc) = make_float4(ov[0], ov[1], ov[2], ov[3]);
    *(float4*)(out + (size_t)gr * DD + gc + 4) = make_float4(ov[4], ov[5], ov[6], ov[7]);
    uint4 p;
    p.x = (unsigned)f2bf(ov[0]) | ((unsigned)f2bf(ov[1]) << 16);
    p.y = (unsigned)f2bf(ov[2]) | ((unsigned)f2bf(ov[3]) << 16);
    p.z = (unsigned)f2bf(ov[4]) | ((unsigned)f2bf(ov[5]) << 16);
    p.w = (unsigned)f2bf(ov[6]) | ((unsigned)f2bf(ov[7]) << 16);
    *(uint4*)(Houtb + (size_t)gr * DD + gc) = p;
  }
}

// ======== K4: lap_smooth via lower edges only (2-deep MLP unroll) =========================
// lap = sum_i ||h_i||^2 (1 - dinv_i^2) - sum_{lower edges (i,j)} 2 dinv_i dinv_j <h_i,h_j>
__global__ __launch_bounds__(256) void lap_rows(const float* __restrict__ Hout,
                                                const unsigned short* __restrict__ Houtb,
                                                const int* __restrict__ lowCols,
                                                const int* __restrict__ lowCnt,
                                                const float* __restrict__ dinv,
                                                float* __restrict__ part) {
  int row = (NN - 1) - blockIdx.x;   // heavy rows first
  int tid = threadIdx.x;
  int lane = tid & 63, wv = tid >> 6;
  __shared__ int scols[CAPL];
  __shared__ float sdinv[CAPL];
  __shared__ float sred[4][260];
  int lcT = lowCnt[row];
  int lc = lcT < CAPL ? lcT : CAPL;
  if (tid < lc) {
    int c = lowCols[(size_t)row * CAPL + tid];
    scols[tid] = c;
    sdinv[tid] = 2.0f * dinv[c];
  }
  __syncthreads();
  float4 accA = make_float4(0.f, 0.f, 0.f, 0.f);
  float4 accB = make_float4(0.f, 0.f, 0.f, 0.f);
  for (int jj = wv; jj < lc; jj += 8) {
    int jB = jj + 4;
    uint2 uA = *(const uint2*)(Houtb + (size_t)scols[jj] * DD + lane * 4);
    if (jB < lc) {
      uint2 uB = *(const uint2*)(Houtb + (size_t)scols[jB] * DD + lane * 4);
      float wB = sdinv[jB];
      accB.x += wB * bflo(uB.x); accB.y += wB * bfhi(uB.x);
      accB.z += wB * bflo(uB.y); accB.w += wB * bfhi(uB.y);
    }
    float wA = sdinv[jj];
    accA.x += wA * bflo(uA.x); accA.y += wA * bfhi(uA.x);
    accA.z += wA * bflo(uA.y); accA.w += wA * bfhi(uA.y);
  }
  accA.x += accB.x; accA.y += accB.y; accA.z += accB.z; accA.w += accB.w;
  *(float4*)(&sred[wv][lane * 4]) = accA;
  __syncthreads();
  if (wv == 0) {
    float4 s4;
    s4.x = sred[0][lane * 4 + 0] + sred[1][lane * 4 + 0] + sred[2][lane * 4 + 0] + sred[3][lane * 4 + 0];
    s4.y = sred[0][lane * 4 + 1] + sred[1][lane * 4 + 1] + sred[2][lane * 4 + 1] + sred[3][lane * 4 + 1];
    s4.z = sred[0][lane * 4 + 2] + sred[1][lane * 4 + 2] + sred[2][lane * 4 + 2] + sred[3][lane * 4 + 2];
    s4.w = sred[0][lane * 4 + 3] + sred[1][lane * 4 + 3] + sred[2][lane * 4 + 3] + sred[3][lane * 4 + 3];
    float4 h4 = *(const float4*)(Hout + (size_t)row * DD + lane * 4);
    float dvr = dinv[row];
    float own = 1.0f - dvr * dvr;
    float val = h4.x * (own * h4.x - dvr * s4.x) + h4.y * (own * h4.y - dvr * s4.y) +
                h4.z * (own * h4.z - dvr * s4.z) + h4.w * (own * h4.w - dvr * s4.w);
#pragma unroll
    for (int off = 32; off > 0; off >>= 1) val += __shfl_xor(val, off);
    if (lane == 0) part[row] = val;
  }
}

// ======== K5: deterministic final reduction ==============================================
__global__ __launch_bounds__(256) void finalize(const float* __restrict__ lap_part,
                                                const float* __restrict__ orth_part,
                                                float* __restrict__ out) {
  __shared__ double red[256];
  int tid = threadIdx.x;
  double s = 0.0;
  for (int i = tid; i < NN; i += 256) s += (double)lap_part[i];
  red[tid] = s;
  __syncthreads();
  for (int off = 128; off > 0; off >>= 1) {
    if (tid < off) red[tid] += red[tid + off];
    __syncthreads();
  }
  if (tid == 0) {
    double o = 0.0;
    for (int i = 0; i < 10; ++i) o += (double)orth_part[i];
    out[(size_t)NN * DD] = (float)o;
    out[(size_t)NN * DD + 1] = (float)red[0];
  }
}

extern "C" void kernel_launch(void* const* d_in, const int* in_sizes, int n_in,
                              void* d_out, int out_size, void* d_ws, size_t ws_size,
                              hipStream_t stream) {
  const float* H = (const float*)d_in[0];
  const float* A = (const float*)d_in[1];
  // d_in[2] (dense L) intentionally unused: L reconstructed exactly from A.
  const float* U = (const float*)d_in[3];
  const float* lambda_p = (const float*)d_in[4];
  const float* thr = (const float*)d_in[5];
  float* out = (float*)d_out;

  char* w = (char*)d_ws;
  float* B2 = (float*)w;             w += (size_t)PP * DD * 4;     // 128 KB
  int* lowCols = (int*)w;            w += (size_t)NN * CAPL * 4;   // 4 MB
  int* upCols = (int*)w;             w += (size_t)NN * CAPL * 4;   // 4 MB
  int* lowCnt = (int*)w;             w += (size_t)NN * 4;
  int* upCnt = (int*)w;              w += (size_t)NN * 4;
  float* dinv = (float*)w;           w += (size_t)NN * 4;
  unsigned short* Zb = (unsigned short*)w;   w += (size_t)NN * PP * 2;   // 2 MB
  unsigned short* Hb = (unsigned short*)w;   w += (size_t)NN * DD * 2;   // 4 MB
  unsigned short* Houtb = (unsigned short*)w; w += (size_t)NN * DD * 2;  // 4 MB
  float* aggZ = (float*)w;           w += (size_t)NN * PP * 4;     // 4 MB
  float* S = (float*)w;              w += (size_t)NN * DD * 4;     // 8 MB
  float* lap_part = (float*)w;       w += (size_t)NN * 4;
  float* orth_part = (float*)w;      w += 64;

  hipMemsetAsync(upCnt, 0, (size_t)NN * 4, stream);   // graph-capturable
  zgemm_scan<<<dim3(650 + NN / 2), dim3(256), 0, stream>>>(A, H, U, B2, Zb, Hb, orth_part,
                                                           lowCols, lowCnt, upCols, upCnt);
  csr_attn_s<<<dim3(NN), dim3(256), 0, stream>>>(Zb, Hb, lowCols, lowCnt, upCols, upCnt,
                                                 dinv, aggZ, S);
  egemm<<<dim3(NN / 32, 2), dim3(256), 0, stream>>>(aggZ, B2, H, S, dinv, thr, lambda_p,
                                                    out, Houtb);
  lap_rows<<<dim3(NN), dim3(256), 0, stream>>>(out, Houtb, lowCols, lowCnt, dinv, lap_part);
  finalize<<<dim3(1), dim3(256), 0, stream>>>(lap_part, orth_part, out);
}